// Round 2
// baseline (61.200 us; speedup 1.0000x reference)
//
#include <hip/hip_runtime.h>

// Problem constants (reference: B=8, T=2000, N=2048, penalty=10.0)
#define B_CONST 8
#define T_CONST 2000
#define N_CONST 2048
#define ZC 80                 // time chunks; blocks = 2*8*80 = 1280 = 5/CU exactly
#define TC (T_CONST / ZC)     // 25 timesteps per thread
#define PENALTY 10.0f

// Partial per (b, n, chunk): (count, t_first, t_last, sum ISI^2) packed in float4.
// Monoid combine (time-ordered): if both nonempty, s2 += (R.first - L.last)^2.
// All quantities are small integers / sums of squares bounded by (sum ISI)^2 < 2^24,
// so every partial is EXACT in fp32 regardless of chunking.

__global__ __launch_bounds__(256) void cv_partial_kernel(const float* __restrict__ x,
                                                         float4* __restrict__ ws,
                                                         float* __restrict__ out) {
    // fold the d_out zero-init into this kernel (saves a memset dispatch);
    // kernel 2 only runs after this kernel fully completes (stream order).
    if (blockIdx.x == 0 && blockIdx.y == 0 && blockIdx.z == 0 && threadIdx.x == 0)
        *out = 0.0f;

    const int n0 = blockIdx.x * 1024 + threadIdx.x * 4;  // 4 consecutive n per thread
    const int b  = blockIdx.y;
    const int z  = blockIdx.z;                           // time chunk 0..ZC-1
    const int t0 = z * TC;

    const float* p = x + ((size_t)b * T_CONST + t0) * (size_t)N_CONST + n0;

    float cnt[4]  = {0.f, 0.f, 0.f, 0.f};
    float frst[4] = {0.f, 0.f, 0.f, 0.f};
    float last[4] = {0.f, 0.f, 0.f, 0.f};
    float s2[4]   = {0.f, 0.f, 0.f, 0.f};

#pragma unroll 5
    for (int i = 0; i < TC; ++i) {
        const float4 v = *reinterpret_cast<const float4*>(p);
        p += N_CONST;
        const float t = (float)(t0 + i);
        const float vv[4] = {v.x, v.y, v.z, v.w};
#pragma unroll
        for (int j = 0; j < 4; ++j) {
            if (vv[j] > 0.0f) {                       // spike
                const float d = t - last[j];
                s2[j]  += (cnt[j] > 0.0f) ? d * d : 0.0f;
                frst[j] = (cnt[j] > 0.0f) ? frst[j] : t;
                last[j] = t;
                cnt[j] += 1.0f;
            }
        }
    }

    // coalesced: each thread writes 4 consecutive float4 = 64 B
    float4* w = ws + ((size_t)(b * ZC + z) * N_CONST) + n0;
#pragma unroll
    for (int j = 0; j < 4; ++j)
        w[j] = make_float4(cnt[j], frst[j], last[j], s2[j]);
}

__global__ __launch_bounds__(64) void cv_final_kernel(const float4* __restrict__ ws,
                                                      const float* __restrict__ tcv,
                                                      float* __restrict__ out) {
    const int gid = blockIdx.x * 64 + threadIdx.x;   // 0 .. B*N-1
    const int b   = gid >> 11;                       // / N_CONST
    const int n   = gid & (N_CONST - 1);

    float mc = 0.f, mf = 0.f, ml = 0.f, ms = 0.f;
#pragma unroll 10
    for (int q = 0; q < ZC; ++q) {
        const float4 pp = ws[((size_t)(b * ZC + q) * N_CONST) + n];  // coalesced per wave
        if (pp.x > 0.0f) {
            if (mc > 0.0f) {
                const float d = pp.y - ml;           // cross-chunk ISI
                ms += pp.w + d * d;
                ml  = pp.z;
                mc += pp.x;
            } else {
                mc = pp.x; mf = pp.y; ml = pp.z; ms = pp.w;
            }
        }
    }

    float cvs;
    if (mc >= 3.0f) {                       // count>=3 implies mean_isi>0 (integer times)
        const float k    = mc - 1.0f;       // number of ISIs
        const float s1   = ml - mf;         // telescoped sum of ISIs (exact)
        const float mean = s1 / k;
        float var = (ms - k * mean * mean) / (k - 1.0f);   // unbiased, same as ref
        var = fmaxf(var, 0.0f);
        cvs = sqrtf(var) / mean;
    } else {
        cvs = PENALTY;
    }
    const float dd = cvs - tcv[n];
    float e = dd * dd;

    // wave64 shuffle reduce, one atomic per block (256 blocks)
#pragma unroll
    for (int o = 32; o > 0; o >>= 1) e += __shfl_down(e, o, 64);
    if (threadIdx.x == 0)
        atomicAdd(out, e * (1.0f / ((float)B_CONST * (float)N_CONST)));
}

extern "C" void kernel_launch(void* const* d_in, const int* in_sizes, int n_in,
                              void* d_out, int out_size, void* d_ws, size_t ws_size,
                              hipStream_t stream) {
    const float* x   = (const float*)d_in[0];   // (B,T,N) fp32
    const float* tcv = (const float*)d_in[1];   // (N,) fp32
    float* out = (float*)d_out;
    float4* ws = (float4*)d_ws;                 // needs B*ZC*N*16 = 21 MB

    dim3 g1(N_CONST / 1024, B_CONST, ZC);       // (2, 8, 80) = 1280 blocks = 5/CU
    cv_partial_kernel<<<g1, dim3(256), 0, stream>>>(x, ws, out);

    cv_final_kernel<<<(B_CONST * N_CONST) / 64, dim3(64), 0, stream>>>(ws, tcv, out);
}

// Round 3
// 35.603 us; speedup vs baseline: 1.7190x; 1.7190x over previous
//
#include <hip/hip_runtime.h>

// Problem constants (reference: B=8, T=2000, N=2048, penalty=10.0)
#define B_CONST 8
#define T_CONST 2000
#define N_CONST 2048
#define ZC 40                 // time chunks; grid (4,8,40)=1280 blocks = 5/CU exactly
#define TC (T_CONST / ZC)     // 50 timesteps per thread
#define CPW (ZC / 4)          // 10 chunks merged per wave in kernel 2
#define PENALTY 10.0f

// Partial per (b, n, chunk): (count, t_first, t_last, sum ISI^2) as float4.
// Monoid combine (time-ordered): if both nonempty, s2 += (R.first - L.last)^2.
// All quantities are integers / sums of squares < 2^24 -> exact in fp32 for
// any chunking, so this matches the reference bit-for-bit per (b,n).

__global__ __launch_bounds__(128) void cv_partial_kernel(const float* __restrict__ x,
                                                         float4* __restrict__ ws,
                                                         float* __restrict__ out) {
    // fold d_out zero-init here (saves a dispatch); kernel 2 is stream-ordered after us
    if (threadIdx.x == 0 && blockIdx.x == 0 && blockIdx.y == 0 && blockIdx.z == 0)
        *out = 0.0f;

    const int n0 = blockIdx.x * 512 + threadIdx.x * 4;  // 4 consecutive n per thread
    const int b  = blockIdx.y;
    const int z  = blockIdx.z;
    const int t0 = z * TC;

    const float* p = x + ((size_t)b * T_CONST + t0) * (size_t)N_CONST + n0;

    float cnt[4]  = {0.f, 0.f, 0.f, 0.f};
    float frst[4] = {0.f, 0.f, 0.f, 0.f};
    float last[4] = {0.f, 0.f, 0.f, 0.f};
    float s2[4]   = {0.f, 0.f, 0.f, 0.f};

#pragma unroll 10
    for (int i = 0; i < TC; ++i) {
        const float4 v = *reinterpret_cast<const float4*>(p);
        p += N_CONST;
        const float t = (float)(t0 + i);
        const float vv[4] = {v.x, v.y, v.z, v.w};
#pragma unroll
        for (int j = 0; j < 4; ++j) {               // branchless: selects only
            const bool sp  = vv[j] > 0.0f;
            const bool has = cnt[j] > 0.0f;
            const float d  = t - last[j];
            s2[j]  += (sp && has) ? d * d : 0.0f;
            frst[j] = (sp && !has) ? t : frst[j];
            last[j] = sp ? t : last[j];
            cnt[j] += sp ? 1.0f : 0.0f;
        }
    }

    float4* w = ws + ((size_t)(b * ZC + z) * N_CONST) + n0;
#pragma unroll
    for (int j = 0; j < 4; ++j)
        w[j] = make_float4(cnt[j], frst[j], last[j], s2[j]);
}

__global__ __launch_bounds__(256) void cv_final_kernel(const float4* __restrict__ ws,
                                                       const float* __restrict__ tcv,
                                                       float* __restrict__ out) {
    const int l   = threadIdx.x & 63;               // lane -> (b,n) item
    const int w   = threadIdx.x >> 6;               // wave -> chunk segment
    const int gid = blockIdx.x * 64 + l;            // 0 .. B*N-1 (64 divides N)
    const int b   = gid >> 11;
    const int n   = gid & (N_CONST - 1);

    // each wave merges its 10 chunks, branchless so loads pipeline
    float mc = 0.f, mf = 0.f, ml = 0.f, ms = 0.f;
    const float4* base = ws + ((size_t)(b * ZC + w * CPW) * N_CONST) + n;
#pragma unroll
    for (int i = 0; i < CPW; ++i) {
        const float4 pp = base[(size_t)i * N_CONST];   // coalesced 1 KB per wave
        const bool hp = pp.x > 0.0f;
        const bool hm = mc > 0.0f;
        const float d  = pp.y - ml;
        const float m2 = ms + pp.w + d * d;
        ms  = hp ? (hm ? m2 : pp.w) : ms;
        mf  = (hp && !hm) ? pp.y : mf;
        ml  = hp ? pp.z : ml;
        mc += hp ? pp.x : 0.0f;
    }

    __shared__ float4 lds[4][64];
    lds[w][l] = make_float4(mc, mf, ml, ms);
    __syncthreads();

    if (w == 0) {
        mc = 0.f; mf = 0.f; ml = 0.f; ms = 0.f;
#pragma unroll
        for (int q = 0; q < 4; ++q) {               // time-ordered 4-way combine
            const float4 pp = lds[q][l];
            const bool hp = pp.x > 0.0f;
            const bool hm = mc > 0.0f;
            const float d  = pp.y - ml;
            const float m2 = ms + pp.w + d * d;
            ms  = hp ? (hm ? m2 : pp.w) : ms;
            mf  = (hp && !hm) ? pp.y : mf;
            ml  = hp ? pp.z : ml;
            mc += hp ? pp.x : 0.0f;
        }

        float cvs;
        if (mc >= 3.0f) {                 // count>=3 implies mean_isi>0 (integer times)
            const float k    = mc - 1.0f;
            const float mean = (ml - mf) / k;          // telescoped sum of ISIs
            const float var  = fmaxf((ms - k * mean * mean) / (k - 1.0f), 0.0f);
            cvs = sqrtf(var) / mean;
        } else {
            cvs = PENALTY;
        }
        const float dd = cvs - tcv[n];
        float e = dd * dd;

#pragma unroll
        for (int o = 32; o > 0; o >>= 1) e += __shfl_down(e, o, 64);
        if (l == 0)
            atomicAdd(out, e * (1.0f / ((float)B_CONST * (float)N_CONST)));
    }
}

extern "C" void kernel_launch(void* const* d_in, const int* in_sizes, int n_in,
                              void* d_out, int out_size, void* d_ws, size_t ws_size,
                              hipStream_t stream) {
    const float* x   = (const float*)d_in[0];   // (B,T,N) fp32
    const float* tcv = (const float*)d_in[1];   // (N,) fp32
    float* out = (float*)d_out;
    float4* ws = (float4*)d_ws;                 // needs B*ZC*N*16 = 10.5 MB

    dim3 g1(N_CONST / 512, B_CONST, ZC);        // (4, 8, 40) = 1280 blocks = 5/CU
    cv_partial_kernel<<<g1, dim3(128), 0, stream>>>(x, ws, out);

    cv_final_kernel<<<(B_CONST * N_CONST) / 64, dim3(256), 0, stream>>>(ws, tcv, out);
}